// Round 1
// baseline (38.899 us; speedup 1.0000x reference)
//
#include <hip/hip_runtime.h>

#define ROW_LEN 512
// one wave (64 lanes) per row; 4 waves per 256-thread block

__device__ __forceinline__ void insert3(float v, float& t0, float& t1, float& t2) {
    // maintain t0 >= t1 >= t2 = top-3 multiset; branchless (compiles to cndmask)
    bool g0 = v > t0;
    bool g1 = v > t1;
    bool g2 = v > t2;
    float n2 = g1 ? t1 : (g2 ? v : t2);
    float n1 = g0 ? t0 : (g1 ? v : t1);
    float n0 = g0 ? v : t0;
    t0 = n0; t1 = n1; t2 = n2;
}

__global__ __launch_bounds__(256) void KmaxLayer_kernel(const float* __restrict__ x,
                                                        float* __restrict__ out,
                                                        int n_rows) {
    const int wave_in_block = threadIdx.x >> 6;
    const int lane = threadIdx.x & 63;
    const int row = blockIdx.x * 4 + wave_in_block;
    if (row >= n_rows) return;

    const float4* __restrict__ xr =
        reinterpret_cast<const float4*>(x + (size_t)row * ROW_LEN);
    // two coalesced 16B loads per lane: covers 512 floats per wave
    float4 a = xr[lane];
    float4 b = xr[lane + 64];

    // per-lane top-3 of its 8 values
    float t0 = -INFINITY, t1 = -INFINITY, t2 = -INFINITY;
    insert3(a.x, t0, t1, t2); insert3(a.y, t0, t1, t2);
    insert3(a.z, t0, t1, t2); insert3(a.w, t0, t1, t2);
    insert3(b.x, t0, t1, t2); insert3(b.y, t0, t1, t2);
    insert3(b.z, t0, t1, t2); insert3(b.w, t0, t1, t2);

    // butterfly all-reduce of top-3 triples across the 64-lane wave
    #pragma unroll
    for (int off = 1; off < 64; off <<= 1) {
        float o0 = __shfl_xor(t0, off);
        float o1 = __shfl_xor(t1, off);
        float o2 = __shfl_xor(t2, off);
        insert3(o0, t0, t1, t2);
        insert3(o1, t0, t1, t2);
        insert3(o2, t0, t1, t2);
    }
    const float kth = t2;  // 3rd largest in the row (min of top-3)

    // masked sum (x >= kth), butterfly add-reduce
    float s = 0.0f;
    s += (a.x >= kth) ? a.x : 0.0f;
    s += (a.y >= kth) ? a.y : 0.0f;
    s += (a.z >= kth) ? a.z : 0.0f;
    s += (a.w >= kth) ? a.w : 0.0f;
    s += (b.x >= kth) ? b.x : 0.0f;
    s += (b.y >= kth) ? b.y : 0.0f;
    s += (b.z >= kth) ? b.z : 0.0f;
    s += (b.w >= kth) ? b.w : 0.0f;
    #pragma unroll
    for (int off = 1; off < 64; off <<= 1)
        s += __shfl_xor(s, off);

    const float inv = 1.0f / s;

    float4 oa, ob;
    oa.x = (a.x >= kth) ? a.x * inv : 0.0f;
    oa.y = (a.y >= kth) ? a.y * inv : 0.0f;
    oa.z = (a.z >= kth) ? a.z * inv : 0.0f;
    oa.w = (a.w >= kth) ? a.w * inv : 0.0f;
    ob.x = (b.x >= kth) ? b.x * inv : 0.0f;
    ob.y = (b.y >= kth) ? b.y * inv : 0.0f;
    ob.z = (b.z >= kth) ? b.z * inv : 0.0f;
    ob.w = (b.w >= kth) ? b.w * inv : 0.0f;

    float4* __restrict__ orow =
        reinterpret_cast<float4*>(out + (size_t)row * ROW_LEN);
    orow[lane] = oa;
    orow[lane + 64] = ob;
}

extern "C" void kernel_launch(void* const* d_in, const int* in_sizes, int n_in,
                              void* d_out, int out_size, void* d_ws, size_t ws_size,
                              hipStream_t stream) {
    const float* x = (const float*)d_in[0];
    float* out = (float*)d_out;
    const int n_rows = in_sizes[0] / ROW_LEN;  // 128*512 = 65536
    const int waves_per_block = 4;             // 256 threads
    const int n_blocks = (n_rows + waves_per_block - 1) / waves_per_block;
    KmaxLayer_kernel<<<n_blocks, 256, 0, stream>>>(x, out, n_rows);
}